// Round 4
// baseline (102.079 us; speedup 1.0000x reference)
//
#include <hip/hip_runtime.h>
#include <hip/hip_bf16.h>

// Problem constants (fixed by setup_inputs): B=4, S=8192, D=1024, E=64, top_k=1
#define NB 4
#define NS 8192
#define ND 1024
#define NE 64
#define NM (NB * NS)          // 32768 tokens
#define CAPACITY 640

#define CHUNK 64              // tokens per capacity-rank chunk (tail kernels)
#define NCHUNK (NM / CHUNK)   // 512
#define CPB (NS / CHUNK)      // 128 chunks per batch

#define BTOK 16               // tokens per block (one MFMA tile)
#define NBLK (NM / BTOK)      // 2048 blocks -> 8 blocks/CU, 32 waves/CU
#define KSEG (ND / 4)         // 256: K-range per wave (K-split across 4 waves)

typedef short short8 __attribute__((ext_vector_type(8)));
typedef float f32x4 __attribute__((ext_vector_type(4)));

// ---------------------------------------------------------------------------
// K0: split W (fp32 [E][D]) into bf16 hi/lo planes (RNE both levels),
// and zero the chunk histogram (k1 accumulates into it atomically).
// 64 blocks x 256 threads.
// ---------------------------------------------------------------------------
__global__ __launch_bounds__(256) void w_conv(const float* __restrict__ W,
                                              unsigned short* __restrict__ Wh,
                                              unsigned short* __restrict__ Wl,
                                              int* __restrict__ hist)
{
    const int t = blockIdx.x * 256 + threadIdx.x;   // 16384 threads
    const int i = t * 4;
    float4 v = *(const float4*)(W + i);
    float f[4] = {v.x, v.y, v.z, v.w};
    ushort4 h, l;
    unsigned short* hp = &h.x;
    unsigned short* lp = &l.x;
#pragma unroll
    for (int c = 0; c < 4; ++c) {
        __hip_bfloat16 hb = __float2bfloat16(f[c]);
        float r = f[c] - __bfloat162float(hb);
        __hip_bfloat16 lb = __float2bfloat16(r);
        hp[c] = __builtin_bit_cast(unsigned short, hb);
        lp[c] = __builtin_bit_cast(unsigned short, lb);
    }
    *(ushort4*)(Wh + i) = h;
    *(ushort4*)(Wl + i) = l;
    // zero hist: 512*64 = 32768 ints, 16384 threads x 8 B
    ((long long*)hist)[t] = 0ll;
}

// ---------------------------------------------------------------------------
// K1: zero-LDS bf16x3-split MFMA GEMM, K-split across the block's 4 waves.
// Block: 256 threads = 4 waves; ALL waves share the block's 16 tokens, wave w
// accumulates K-segment [w*256, w*256+256). Partials reduced via padded LDS;
// wave 0 runs the fused softmax-top1 epilogue.
// C/D layout (verified m89/m91): col = lane&15 (expert), row = (lane>>4)*4+reg.
// ---------------------------------------------------------------------------
__global__ __launch_bounds__(256, 8) void k1_mfma(const float* __restrict__ x,
                                                  const short* __restrict__ Wh,
                                                  const short* __restrict__ Wl,
                                                  float* __restrict__ logits,
                                                  float* __restrict__ e_out,
                                                  float* __restrict__ p_out,
                                                  int* __restrict__ idx_ws,
                                                  float* __restrict__ prob_ws,
                                                  int* __restrict__ hist)
{
    __shared__ float red[3 * 64 * 20];   // 3 waves' partials, 20-float lane stride (80 B)

    const int tid = threadIdx.x;
    const int lane = tid & 63;
    const int wv = tid >> 6;       // K-segment 0..3
    const int lr = lane & 15;
    const int kq = lane >> 4;
    const int tok_base = blockIdx.x * BTOK;

    // vectorized zero-fill of the sparse outputs for this block's 16 tokens
    {
        const float4 z = {0.f, 0.f, 0.f, 0.f};
        size_t o = (size_t)tok_base * NE + tid * 4;   // 1024 floats, 256 thr x 4
        *(float4*)&e_out[o] = z;
        *(float4*)&p_out[o] = z;
    }

    const size_t kof = (size_t)(wv * KSEG + kq * 8);
    const float* xrow = x + (size_t)(tok_base + lr) * ND + kof;
    const short* wh0 = Wh + (size_t)lr * ND + kof;
    const short* wl0 = Wl + (size_t)lr * ND + kof;

    f32x4 acc[4];
#pragma unroll
    for (int j = 0; j < 4; ++j) acc[j] = (f32x4){0.f, 0.f, 0.f, 0.f};

    for (int k0 = 0; k0 < KSEG; k0 += 32) {
        // A: 8 fp32 of this lane's fragment, split to bf16 hi/lo in-register
        float4 v0 = *(const float4*)(xrow + k0);
        float4 v1 = *(const float4*)(xrow + k0 + 4);
        float f[8] = {v0.x, v0.y, v0.z, v0.w, v1.x, v1.y, v1.z, v1.w};
        short8 ah, al;
#pragma unroll
        for (int c = 0; c < 8; ++c) {
            __hip_bfloat16 hb = __float2bfloat16(f[c]);
            float r = f[c] - __bfloat162float(hb);
            __hip_bfloat16 lb = __float2bfloat16(r);
            ah[c] = __builtin_bit_cast(short, hb);
            al[c] = __builtin_bit_cast(short, lb);
        }
        // B: 4 expert groups, hi+lo, straight from global (L2-resident)
        short8 bh[4], bl[4];
#pragma unroll
        for (int j = 0; j < 4; ++j) {
            bh[j] = *(const short8*)(wh0 + (size_t)(j * 16) * ND + k0);
            bl[j] = *(const short8*)(wl0 + (size_t)(j * 16) * ND + k0);
        }
#pragma unroll
        for (int j = 0; j < 4; ++j) {
            acc[j] = __builtin_amdgcn_mfma_f32_16x16x32_bf16(ah, bh[j], acc[j], 0, 0, 0);
            acc[j] = __builtin_amdgcn_mfma_f32_16x16x32_bf16(ah, bl[j], acc[j], 0, 0, 0);
            acc[j] = __builtin_amdgcn_mfma_f32_16x16x32_bf16(al, bh[j], acc[j], 0, 0, 0);
        }
    }

    // ---- cross-wave K reduction (padded LDS: 80 B lane stride, <=2-way banks)
    if (wv > 0) {
        float* dst = &red[((wv - 1) * 64 + lane) * 20];
#pragma unroll
        for (int j = 0; j < 4; ++j) *(f32x4*)(dst + j * 4) = acc[j];
    }
    __syncthreads();

    if (wv == 0) {
#pragma unroll
        for (int w = 0; w < 3; ++w) {
            const float* srcp = &red[(w * 64 + lane) * 20];
#pragma unroll
            for (int j = 0; j < 4; ++j) acc[j] += *(const f32x4*)(srcp + j * 4);
        }

        // ---- fused epilogue: per-token softmax top-1 (16 tokens, wave 0 only)
#pragma unroll
        for (int r = 0; r < 4; ++r) {
            const int t = tok_base + kq * 4 + r;
            float val[4];
#pragma unroll
            for (int j = 0; j < 4; ++j) val[j] = acc[j][r];

            // local argmax over j (ascending j + strict > keeps lowest expert)
            float m = val[0];
            int mi = lr;
#pragma unroll
            for (int j = 1; j < 4; ++j) {
                if (val[j] > m) { m = val[j]; mi = j * 16 + lr; }
            }
            // butterfly across the 16 lanes of this fragment-row group
#pragma unroll
            for (int off = 1; off < 16; off <<= 1) {
                float m2 = __shfl_xor(m, off);
                int mi2 = __shfl_xor(mi, off);
                if (m2 > m || (m2 == m && mi2 < mi)) { m = m2; mi = mi2; }
            }
            // softmax denominator
            float s = 0.0f;
#pragma unroll
            for (int j = 0; j < 4; ++j) s += __expf(val[j] - m);
#pragma unroll
            for (int off = 1; off < 16; off <<= 1) s += __shfl_xor(s, off);

            // write logits
#pragma unroll
            for (int j = 0; j < 4; ++j) {
                logits[(size_t)t * NE + j * 16 + lr] = val[j];
            }
            if (lr == 0) {
                idx_ws[t] = mi;
                prob_ws[t] = 1.0f / s;
                atomicAdd(&hist[(blockIdx.x >> 2) * NE + mi], 1);
            }
        }
    }
}

// ---------------------------------------------------------------------------
// K2: exclusive scan of per-chunk histograms along each batch's 128 chunks
// ---------------------------------------------------------------------------
__global__ __launch_bounds__(64) void k_scan(const int* __restrict__ hist,
                                             int* __restrict__ base)
{
    const int b = blockIdx.x;     // batch
    const int e = threadIdx.x;    // expert
    int run = 0;
    for (int c = 0; c < CPB; ++c) {
        int idx = (b * CPB + c) * NE + e;
        base[idx] = run;
        run += hist[idx];
    }
}

// ---------------------------------------------------------------------------
// K3: per-chunk ordered rank + scatter. One wave per 64-token chunk.
// rank is INCLUSIVE (matches cumsum <= CAPACITY).
// ---------------------------------------------------------------------------
__global__ __launch_bounds__(64) void k_scatter(const int* __restrict__ idx_ws,
                                                const float* __restrict__ prob_ws,
                                                const int* __restrict__ base,
                                                float* __restrict__ e_out,
                                                float* __restrict__ p_out)
{
    __shared__ int sIdx[CHUNK];
    __shared__ float sProb[CHUNK];
    const int c = blockIdx.x;
    const int lane = threadIdx.x;
    const int t0 = c * CHUNK;
    sIdx[lane] = idx_ws[t0 + lane];
    sProb[lane] = prob_ws[t0 + lane];
    __syncthreads();

    int counter = base[c * NE + lane];
    for (int j = 0; j < CHUNK; ++j) {
        if (sIdx[j] == lane) {
            ++counter;
            if (counter <= CAPACITY) {
                size_t g = (size_t)(t0 + j) * NE + lane;
                e_out[g] = 1.0f;
                p_out[g] = sProb[j];
            }
        }
    }
}

// ---------------------------------------------------------------------------
extern "C" void kernel_launch(void* const* d_in, const int* in_sizes, int n_in,
                              void* d_out, int out_size, void* d_ws, size_t ws_size,
                              hipStream_t stream)
{
    const float* x = (const float*)d_in[0];   // [B,S,D] fp32
    const float* W = (const float*)d_in[1];   // [E,D] fp32
    // d_in[2] = top_k (==1), ignored

    float* out = (float*)d_out;
    float* e_out = out;                          // expert_indices as 0.0/1.0
    float* p_out = out + (size_t)NM * NE;        // router_probs
    float* logits = out + 2 * (size_t)NM * NE;   // logits

    char* ws = (char*)d_ws;
    int* idx_ws    = (int*)ws;                                   // NM ints   (128 KB)
    float* prob_ws = (float*)(ws + (size_t)NM * 4);              // NM floats (128 KB)
    int* hist      = (int*)(ws + (size_t)NM * 8);                // 512*64    (128 KB)
    int* base      = (int*)(ws + (size_t)NM * 8 + (size_t)NCHUNK * NE * 4); // (128 KB)
    unsigned short* Wh = (unsigned short*)(ws + (size_t)NM * 8 + (size_t)NCHUNK * NE * 8);
    unsigned short* Wl = Wh + (size_t)NE * ND;                   // 128 KB each

    w_conv<<<NE * ND / (256 * 4), 256, 0, stream>>>(W, Wh, Wl, hist);
    k1_mfma<<<NBLK, 256, 0, stream>>>(x, (const short*)Wh, (const short*)Wl,
                                      logits, e_out, p_out, idx_ws, prob_ws, hist);
    k_scan<<<NB, 64, 0, stream>>>(hist, base);
    k_scatter<<<NCHUNK, 64, 0, stream>>>(idx_ws, prob_ws, base, e_out, p_out);
}

// Round 5
// 55.092 us; speedup vs baseline: 1.8529x; 1.8529x over previous
//
#include <hip/hip_runtime.h>
#include <hip/hip_bf16.h>

// Problem constants (fixed by setup_inputs): B=4, S=8192, D=1024, E=64, top_k=1
#define NB 4
#define NS 8192
#define ND 1024
#define NE 64
#define NM (NB * NS)          // 32768 tokens
#define CAPACITY 640

#define BM 64                 // tokens per block == chunk size
#define BK 64                 // K-tile
#define NKT (ND / BK)         // 16 K-tiles
#define NCHUNK (NM / BM)      // 512 chunks
#define CPB (NS / BM)         // 128 chunks per batch

typedef short short8 __attribute__((ext_vector_type(8)));
typedef unsigned short ushort8 __attribute__((ext_vector_type(8)));
typedef float f32x4 __attribute__((ext_vector_type(4)));

// LDS swizzle: flat short-index within a [64 rows][64 shorts] tile.
// Row stride 128 B would put all rows on the same banks; XOR bits 3-5 of the
// column with (row&7) spreads each column slice across 8 distinct 16-B slots.
__device__ __forceinline__ int swz(int row, int colshorts) {
    return row * 64 + (colshorts ^ ((row & 7) << 3));
}

// ---------------------------------------------------------------------------
// K0: split W (fp32 [E][D]) into bf16 hi/lo planes (RNE both levels).
// Plain [e][k] layout; 64 blocks x 256 threads x 4 elems.
// ---------------------------------------------------------------------------
__global__ __launch_bounds__(256) void w_conv(const float* __restrict__ W,
                                              unsigned short* __restrict__ Wh,
                                              unsigned short* __restrict__ Wl)
{
    const int i = (blockIdx.x * 256 + threadIdx.x) * 4;
    float4 v = *(const float4*)(W + i);
    float f[4] = {v.x, v.y, v.z, v.w};
    ushort4 h, l;
    unsigned short* hp = &h.x;
    unsigned short* lp = &l.x;
#pragma unroll
    for (int c = 0; c < 4; ++c) {
        __hip_bfloat16 hb = __float2bfloat16(f[c]);
        float r = f[c] - __bfloat162float(hb);
        __hip_bfloat16 lb = __float2bfloat16(r);
        hp[c] = __builtin_bit_cast(unsigned short, hb);
        lp[c] = __builtin_bit_cast(unsigned short, lb);
    }
    *(ushort4*)(Wh + i) = h;
    *(ushort4*)(Wl + i) = l;
}

// ---------------------------------------------------------------------------
// K1: LDS-tiled bf16x3-split MFMA GEMM + fused softmax-top1 epilogue.
// Block: 256 threads = 4 waves; BM=64 tokens x 64 experts, 16 K-tiles of 64.
// Wave w owns tokens [tok0 + w*16, +16) over the FULL K (no cross-wave sum).
// x: register-prefetched (depth 1), trunc-split to bf16 hi/lo, ds_write to
// swizzled LDS. W: pre-split planes, reg-staged to swizzled LDS.
// Per K-tile per wave: 20 ds_read_b128 + 24 MFMA(16x16x32).
// C/D layout (verified m89/m91): col = lane&15 (expert), row = (lane>>4)*4+reg.
// ---------------------------------------------------------------------------
__global__ __launch_bounds__(256) void k1_mfma(const float* __restrict__ x,
                                               const unsigned short* __restrict__ Wh,
                                               const unsigned short* __restrict__ Wl,
                                               float* __restrict__ logits,
                                               float* __restrict__ e_out,
                                               float* __restrict__ p_out,
                                               int* __restrict__ idx_ws,
                                               float* __restrict__ prob_ws,
                                               int* __restrict__ hist)
{
    __shared__ short xs_h[64 * 64];   // 8 KB
    __shared__ short xs_l[64 * 64];
    __shared__ short whs[64 * 64];
    __shared__ short wls[64 * 64];
    __shared__ int lh[NE];

    const int tid = threadIdx.x;
    const int lane = tid & 63;
    const int wv = tid >> 6;
    const int lr = lane & 15;
    const int kq = lane >> 4;
    const int tok0 = blockIdx.x * BM;
    const int wtok = tok0 + wv * 16;

    if (tid < NE) lh[tid] = 0;

    // zero-fill sparse outputs for this block's 64 tokens (4096 floats each)
    {
        const float4 z = {0.f, 0.f, 0.f, 0.f};
        size_t b0 = (size_t)tok0 * NE;
#pragma unroll
        for (int i = 0; i < 4; ++i) {
            *(float4*)&e_out[b0 + (size_t)(i * 256 + tid) * 4] = z;
            *(float4*)&p_out[b0 + (size_t)(i * 256 + tid) * 4] = z;
        }
    }

    // x staging coords: row = tid>>2 (0..63), col group = (tid&3)*16
    const int xrow = tid >> 2;
    const int xcol = (tid & 3) * 16;
    const float* xsrc = x + (size_t)(tok0 + xrow) * ND + xcol;

    // W staging coords: per plane-instr i in {0,1}: e = (tid>>3)+i*32, col=(tid&7)*8
    const int we0 = tid >> 3;
    const int wcol = (tid & 7) * 8;

    f32x4 acc[4];
#pragma unroll
    for (int j = 0; j < 4; ++j) acc[j] = (f32x4){0.f, 0.f, 0.f, 0.f};

    // prefetch x tile 0
    float4 px[4], px2[4];
#pragma unroll
    for (int c = 0; c < 4; ++c) px[c] = *(const float4*)(xsrc + c * 4);

    for (int kt = 0; kt < NKT; ++kt) {
        const int k0 = kt * BK;
        if (kt > 0) __syncthreads();   // all waves done reading previous tile

        // ---- stage W planes (pure copy from pre-split, swizzled ds_write)
#pragma unroll
        for (int i = 0; i < 2; ++i) {
            const int e = we0 + i * 32;
            const size_t gs = (size_t)e * ND + k0 + wcol;
            ushort8 vh = *(const ushort8*)(Wh + gs);
            ushort8 vl = *(const ushort8*)(Wl + gs);
            *(ushort8*)&whs[swz(e, wcol)] = vh;
            *(ushort8*)&wls[swz(e, wcol)] = vl;
        }

        // ---- stage x: trunc-split px -> hi/lo, swizzled ds_write (8 B each)
#pragma unroll
        for (int c = 0; c < 4; ++c) {
            float f[4] = {px[c].x, px[c].y, px[c].z, px[c].w};
            ushort4 h4, l4;
            unsigned short* hp = &h4.x;
            unsigned short* lp = &l4.x;
#pragma unroll
            for (int e = 0; e < 4; ++e) {
                unsigned int u = __builtin_bit_cast(unsigned int, f[e]);
                hp[e] = (unsigned short)(u >> 16);
                float fhi = __builtin_bit_cast(float, u & 0xFFFF0000u);
                lp[e] = (unsigned short)(__builtin_bit_cast(unsigned int, f[e] - fhi) >> 16);
            }
            const int si = swz(xrow, xcol + c * 4);
            *(ushort4*)&xs_h[si] = h4;
            *(ushort4*)&xs_l[si] = l4;
        }

        // ---- prefetch next x tile (in flight during the MFMA phase)
        if (kt + 1 < NKT) {
#pragma unroll
            for (int c = 0; c < 4; ++c)
                px2[c] = *(const float4*)(xsrc + (k0 + BK) + c * 4);
        }

        __syncthreads();   // tile ready

        // ---- fragments + MFMA
#pragma unroll
        for (int kk = 0; kk < 2; ++kk) {
            const int col = kk * 32 + kq * 8;
            const int arow = wv * 16 + lr;
            short8 ah = *(const short8*)&xs_h[swz(arow, col)];
            short8 al = *(const short8*)&xs_l[swz(arow, col)];
#pragma unroll
            for (int j = 0; j < 4; ++j) {
                const int erow = j * 16 + lr;
                short8 bh = *(const short8*)&whs[swz(erow, col)];
                short8 bl = *(const short8*)&wls[swz(erow, col)];
                acc[j] = __builtin_amdgcn_mfma_f32_16x16x32_bf16(ah, bh, acc[j], 0, 0, 0);
                acc[j] = __builtin_amdgcn_mfma_f32_16x16x32_bf16(ah, bl, acc[j], 0, 0, 0);
                acc[j] = __builtin_amdgcn_mfma_f32_16x16x32_bf16(al, bh, acc[j], 0, 0, 0);
            }
        }

#pragma unroll
        for (int c = 0; c < 4; ++c) px[c] = px2[c];
    }

    // ---- fused epilogue: per-token softmax top-1 (each wave: its 16 tokens)
#pragma unroll
    for (int r = 0; r < 4; ++r) {
        const int t = wtok + kq * 4 + r;
        float val[4];
#pragma unroll
        for (int j = 0; j < 4; ++j) val[j] = acc[j][r];

        // local argmax over j (ascending j + strict > keeps lowest expert)
        float m = val[0];
        int mi = lr;
#pragma unroll
        for (int j = 1; j < 4; ++j) {
            if (val[j] > m) { m = val[j]; mi = j * 16 + lr; }
        }
        // butterfly across the 16 lanes of this fragment-row group
#pragma unroll
        for (int off = 1; off < 16; off <<= 1) {
            float m2 = __shfl_xor(m, off);
            int mi2 = __shfl_xor(mi, off);
            if (m2 > m || (m2 == m && mi2 < mi)) { m = m2; mi = mi2; }
        }
        // softmax denominator
        float s = 0.0f;
#pragma unroll
        for (int j = 0; j < 4; ++j) s += __expf(val[j] - m);
#pragma unroll
        for (int off = 1; off < 16; off <<= 1) s += __shfl_xor(s, off);

        // write logits
#pragma unroll
        for (int j = 0; j < 4; ++j) {
            logits[(size_t)t * NE + j * 16 + lr] = val[j];
        }
        if (lr == 0) {
            idx_ws[t] = mi;
            prob_ws[t] = 1.0f / s;
            atomicAdd(&lh[mi], 1);
        }
    }
    __syncthreads();
    if (tid < NE) hist[blockIdx.x * NE + tid] = lh[tid];
}

// ---------------------------------------------------------------------------
// K2: exclusive scan of per-chunk histograms. One block, 256 threads:
// thread = (batch b = tid>>6, expert e = tid&63), serial over 128 chunks.
// unroll-8 lets the compiler keep ~8 independent loads in flight.
// ---------------------------------------------------------------------------
__global__ __launch_bounds__(256) void k_scan(const int* __restrict__ hist,
                                              int* __restrict__ base)
{
    const int b = threadIdx.x >> 6;
    const int e = threadIdx.x & 63;
    int run = 0;
#pragma unroll 8
    for (int c = 0; c < CPB; ++c) {
        int idx = (b * CPB + c) * NE + e;
        base[idx] = run;
        run += hist[idx];
    }
}

// ---------------------------------------------------------------------------
// K3: per-chunk ordered rank + scatter. One wave per 64-token chunk.
// rank is INCLUSIVE (matches cumsum <= CAPACITY).
// ---------------------------------------------------------------------------
__global__ __launch_bounds__(64) void k_scatter(const int* __restrict__ idx_ws,
                                                const float* __restrict__ prob_ws,
                                                const int* __restrict__ base,
                                                float* __restrict__ e_out,
                                                float* __restrict__ p_out)
{
    __shared__ int sIdx[BM];
    __shared__ float sProb[BM];
    const int c = blockIdx.x;
    const int lane = threadIdx.x;
    const int t0 = c * BM;
    sIdx[lane] = idx_ws[t0 + lane];
    sProb[lane] = prob_ws[t0 + lane];
    __syncthreads();

    int counter = base[c * NE + lane];
    for (int j = 0; j < BM; ++j) {
        if (sIdx[j] == lane) {
            ++counter;
            if (counter <= CAPACITY) {
                size_t g = (size_t)(t0 + j) * NE + lane;
                e_out[g] = 1.0f;
                p_out[g] = sProb[j];
            }
        }
    }
}

// ---------------------------------------------------------------------------
extern "C" void kernel_launch(void* const* d_in, const int* in_sizes, int n_in,
                              void* d_out, int out_size, void* d_ws, size_t ws_size,
                              hipStream_t stream)
{
    const float* x = (const float*)d_in[0];   // [B,S,D] fp32
    const float* W = (const float*)d_in[1];   // [E,D] fp32
    // d_in[2] = top_k (==1), ignored

    float* out = (float*)d_out;
    float* e_out = out;                          // expert_indices as 0.0/1.0
    float* p_out = out + (size_t)NM * NE;        // router_probs
    float* logits = out + 2 * (size_t)NM * NE;   // logits

    char* ws = (char*)d_ws;
    int* idx_ws    = (int*)ws;                                   // 128 KB
    float* prob_ws = (float*)(ws + (size_t)NM * 4);              // 128 KB
    int* hist      = (int*)(ws + (size_t)NM * 8);                // 128 KB
    int* base      = (int*)(ws + (size_t)NM * 8 + (size_t)NCHUNK * NE * 4); // 128 KB
    unsigned short* Wh = (unsigned short*)(ws + (size_t)NM * 8 + (size_t)NCHUNK * NE * 8);
    unsigned short* Wl = Wh + (size_t)NE * ND;                   // 128 KB each

    w_conv<<<NE * ND / (256 * 4), 256, 0, stream>>>(W, Wh, Wl);
    k1_mfma<<<NM / BM, 256, 0, stream>>>(x, Wh, Wl, logits, e_out, p_out,
                                         idx_ws, prob_ws, hist);
    k_scan<<<1, 256, 0, stream>>>(hist, base);
    k_scatter<<<NCHUNK, 64, 0, stream>>>(idx_ws, prob_ws, base, e_out, p_out);
}